// Round 6
// baseline (923.287 us; speedup 1.0000x reference)
//
#include <hip/hip_runtime.h>
#include <hip/hip_bf16.h>

typedef __bf16 bf16_t;
typedef __bf16 bf16x8 __attribute__((ext_vector_type(8)));
typedef float  f32x4  __attribute__((ext_vector_type(4)));
typedef unsigned int u32x4 __attribute__((ext_vector_type(4)));

#define NB 2
#define NS 2048
#define ND 1024
#define NH 16
#define NDH 64
#define NP 1024
#define NM (NB*NS)   // 4096 rows total

#define MFMA16 __builtin_amdgcn_mfma_f32_16x16x32_bf16

__device__ __forceinline__ bf16x8 load8(const bf16_t* p) {
  u32x4 u = *(const u32x4*)p;
  return __builtin_bit_cast(bf16x8, u);
}
__device__ __forceinline__ unsigned short bfb(float f) {
  return __builtin_bit_cast(unsigned short, (bf16_t)f);
}
// async global->LDS, 16B per lane; LDS dest must be wave-uniform base
__device__ __forceinline__ void gld16(const bf16_t* g, bf16_t* l) {
  __builtin_amdgcn_global_load_lds(
      (const __attribute__((address_space(1))) void*)g,
      (__attribute__((address_space(3))) void*)l, 16, 0, 0);
}

// ---------------------------------------------------------------------------
// Cast x -> bf16 (coalesced float4 -> ushort4)
// ---------------------------------------------------------------------------
__global__ __launch_bounds__(256) void k_cast(
    const float* __restrict__ x, bf16_t* __restrict__ x_bf)
{
  const long NX4 = (long)NM * ND / 4;   // 1M float4 items
  long i0 = (long)blockIdx.x * blockDim.x + threadIdx.x;
  long stride = (long)gridDim.x * blockDim.x;
  for (long i = i0; i < NX4; i += stride) {
    float4 v = ((const float4*)x)[i];
    ushort4 pk;
    pk.x = bfb(v.x); pk.y = bfb(v.y); pk.z = bfb(v.z); pk.w = bfb(v.w);
    ((ushort4*)x_bf)[i] = pk;
  }
}

// ---------------------------------------------------------------------------
// Weight transpose via LDS tile: fp32 [K][N] -> bf16 [N][K], coalesced both ways
// ---------------------------------------------------------------------------
__global__ __launch_bounds__(256) void k_wt(
    const float* __restrict__ Wq, const float* __restrict__ Wk,
    const float* __restrict__ Wv, const float* __restrict__ Wo,
    bf16_t* __restrict__ wtq, bf16_t* __restrict__ wtk,
    bf16_t* __restrict__ wtv, bf16_t* __restrict__ wto)
{
  __shared__ __align__(16) bf16_t tileT[64][72];  // [n][k], stride 144B
  const int w = blockIdx.z;
  const float* src = (w == 0) ? Wq : (w == 1) ? Wk : (w == 2) ? Wv : Wo;
  bf16_t*      dst = (w == 0) ? wtq : (w == 1) ? wtk : (w == 2) ? wtv : wto;
  const int k0 = blockIdx.x * 64, n0 = blockIdx.y * 64;
  const int tid = threadIdx.x;
  const int r = tid >> 4, c4 = (tid & 15) * 4;
#pragma unroll
  for (int rr = 0; rr < 4; ++rr) {
    const int row = rr * 16 + r;                  // k index within tile
    const float4 v = *(const float4*)&src[(long)(k0 + row) * NP + n0 + c4];
    tileT[c4 + 0][row] = (bf16_t)v.x;
    tileT[c4 + 1][row] = (bf16_t)v.y;
    tileT[c4 + 2][row] = (bf16_t)v.z;
    tileT[c4 + 3][row] = (bf16_t)v.w;
  }
  __syncthreads();
  const int nr = tid >> 2, kc = (tid & 3) * 16;
  const bf16x8 p0 = *(const bf16x8*)&tileT[nr][kc];
  const bf16x8 p1 = *(const bf16x8*)&tileT[nr][kc + 8];
  bf16_t* dp = dst + (long)(n0 + nr) * ND + k0 + kc;
  *(bf16x8*)dp = p0;
  *(bf16x8*)(dp + 8) = p1;
}

// ---------------------------------------------------------------------------
// m97-style 128x128 GEMM core: C = A[M x K] * Bt[N x K]^T, bf16 in, f32 acc.
// ---------------------------------------------------------------------------
template <int KDIM>
__device__ __forceinline__ void gemm_128x128(
    const bf16_t* __restrict__ A, const bf16_t* __restrict__ B,
    int tm, int tn, bf16_t (&As)[128][64], bf16_t (&Bs)[128][64],
    f32x4 (&acc)[4][4])
{
  const int wave = threadIdx.x >> 6, lane = threadIdx.x & 63;
  const int l16 = lane & 15, quad = lane >> 4;
  const int wr = wave >> 1, wc = wave & 1;
  const int srcrow = lane >> 3, srccol = (lane & 7) * 8;

  for (int ks = 0; ks < KDIM; ks += 64) {
#pragma unroll
    for (int i = 0; i < 4; ++i) {
      const int cc = i * 4 + wave;   // wave-uniform LDS dest
      gld16(A + (long)(tm + cc * 8 + srcrow) * KDIM + ks + srccol, &As[cc * 8][0]);
      gld16(B + (long)(tn + cc * 8 + srcrow) * KDIM + ks + srccol, &Bs[cc * 8][0]);
    }
    __syncthreads();   // drains vmcnt -> LDS tiles ready
#pragma unroll
    for (int s = 0; s < 2; ++s) {
      bf16x8 aF[4], bF[4];
#pragma unroll
      for (int t = 0; t < 4; ++t)
        aF[t] = load8(&As[wr * 64 + t * 16 + l16][s * 32 + quad * 8]);
#pragma unroll
      for (int t = 0; t < 4; ++t)
        bF[t] = load8(&Bs[wc * 64 + t * 16 + l16][s * 32 + quad * 8]);
#pragma unroll
      for (int mi = 0; mi < 4; ++mi)
#pragma unroll
        for (int ni = 0; ni < 4; ++ni)
          acc[mi][ni] = MFMA16(aF[mi], bF[ni], acc[mi][ni], 0, 0, 0);
    }
    __syncthreads();   // before next stage overwrites LDS
  }
}

// ---------------------------------------------------------------------------
// QKV projection: 128x128 LDS-staged GEMM. q pre-scaled 1/8 (exact pow2);
// q,k stored [b][h][s][dh]; v transposed [b][h][dh][s].
// ---------------------------------------------------------------------------
__global__ __launch_bounds__(256) void k_gemm_proj(
    const bf16_t* __restrict__ Abf,
    const bf16_t* __restrict__ wtq, const bf16_t* __restrict__ wtk,
    const bf16_t* __restrict__ wtv,
    bf16_t* __restrict__ q_ws, bf16_t* __restrict__ k_ws, bf16_t* __restrict__ v_ws)
{
  __shared__ __align__(16) bf16_t As[128][64];
  __shared__ __align__(16) bf16_t Bs[128][64];
  const int z = blockIdx.z;
  const bf16_t* Wt = (z == 0) ? wtq : (z == 1) ? wtk : wtv;
  const int tm = blockIdx.x * 128, tn = blockIdx.y * 128;

  f32x4 acc[4][4];
#pragma unroll
  for (int i = 0; i < 4; ++i)
#pragma unroll
    for (int j = 0; j < 4; ++j) acc[i][j] = (f32x4){0.f, 0.f, 0.f, 0.f};

  gemm_128x128<ND>(Abf, Wt, tm, tn, As, Bs, acc);

  const int wave = threadIdx.x >> 6, lane = threadIdx.x & 63;
  const int l16 = lane & 15, quad = lane >> 4;
  const int wr = wave >> 1, wc = wave & 1;
  const float qscale = (z == 0) ? 0.125f : 1.0f;
#pragma unroll
  for (int mi = 0; mi < 4; ++mi) {
    const int m0 = tm + wr * 64 + mi * 16 + quad * 4;
#pragma unroll
    for (int ni = 0; ni < 4; ++ni) {
      const int n = tn + wc * 64 + ni * 16 + l16;
      const int h = n >> 6, dh = n & 63;
      if (z == 2) {
        const int b = m0 >> 11, s0 = m0 & 2047;
        ushort4 pk;
        pk.x = bfb(acc[mi][ni][0]); pk.y = bfb(acc[mi][ni][1]);
        pk.z = bfb(acc[mi][ni][2]); pk.w = bfb(acc[mi][ni][3]);
        *(ushort4*)(v_ws + ((long)(b * NH + h) * NDH + dh) * NS + s0) = pk;
      } else {
        bf16_t* dst = (z == 0) ? q_ws : k_ws;
#pragma unroll
        for (int r = 0; r < 4; ++r) {
          const int m = m0 + r;
          const int b = m >> 11, s = m & 2047;
          dst[((long)(b * NH + h) * NS + s) * NDH + dh] = (bf16_t)(acc[mi][ni][r] * qscale);
        }
      }
    }
  }
}

// ---------------------------------------------------------------------------
// Fused attention, SINGLE QK sweep, full row-block e in fp32 LDS, 16 WAVES.
// Block = 16 q-rows x one head, 1024 threads (16 waves), 1 block/CU (145 KB),
// -> 16 waves/CU = 4/SIMD (2x round-5 concurrency, same total work).
//   phase 1: wave w computes QK+exp for k in [w*128, w*128+128), writes
//            unnormalized e to eT[16][2048] (fp32), accumulates rowsum parts.
//   barrier; rowsums combined in LDS.
//   phase 3 (issued first): wave w streams normalized attn row w from LDS —
//            contiguous 8 KB per row, 1 KB per store instr.
//   phase 2: PV with UNNORMALIZED e (normalization commutes into O):
//            wave (kh,dt): k-quarter kh (512) x dh-block dt; cross-wave
//            reduce over 4 kh groups via LDS; O *= inv at store.
// ---------------------------------------------------------------------------
__global__ __launch_bounds__(1024) void k_attn_pv(
    const bf16_t* __restrict__ q_ws, const bf16_t* __restrict__ k_ws,
    const bf16_t* __restrict__ v_ws, const int* __restrict__ mask,
    float* __restrict__ attn, bf16_t* __restrict__ o_ws)
{
  constexpr int EP = 2052;                      // padded row stride (dwords), 16B-mult
  __shared__ __align__(16) float eT[16][EP];    // 131,328 B unnormalized exp
  __shared__ float sSum[16][16];                // [wave][row] rowsum partials
  __shared__ __align__(16) float red[3][4][64][4]; // kh=1..3 PV partials (12 KB)
  const int qt = blockIdx.x, h = blockIdx.y, b = blockIdx.z;
  const int wave = threadIdx.x >> 6, lane = threadIdx.x & 63;
  const int l16 = lane & 15, quad = lane >> 4;
  const int qbase = qt * 16;
  const long headoff = (long)(b * NH + h) * NS;
  const bf16_t* qhead = q_ws + headoff * NDH;
  const bf16_t* khead = k_ws + headoff * NDH;
  const bf16_t* vhead = v_ws + (long)(b * NH + h) * NDH * NS;
  const bf16x8 aq0 = load8(qhead + (long)(qbase + l16) * NDH + quad * 8);
  const bf16x8 aq1 = load8(qhead + (long)(qbase + l16) * NDH + 32 + quad * 8);
  const int* mrow = mask + b * NS;

  // ---- phase 1: one QK+exp pass over this wave's 128-k slice ----
  float s0 = 0.f, s1 = 0.f, s2 = 0.f, s3 = 0.f;
  const int kb1 = wave * 128;
#pragma unroll
  for (int k0i = 0; k0i < 2; ++k0i) {
    const int k0 = kb1 + k0i * 64;
#pragma unroll
    for (int nt = 0; nt < 4; ++nt) {
      const bf16_t* kr = khead + (long)(k0 + nt * 16 + l16) * NDH;
      f32x4 acc = {0.f, 0.f, 0.f, 0.f};
      acc = MFMA16(aq0, load8(kr + quad * 8), acc, 0, 0, 0);
      acc = MFMA16(aq1, load8(kr + 32 + quad * 8), acc, 0, 0, 0);
      const int col = k0 + nt * 16 + l16;
      const int mv = mrow[col];
      float e0 = mv ? __expf(acc[0]) : 0.f;
      float e1 = mv ? __expf(acc[1]) : 0.f;
      float e2 = mv ? __expf(acc[2]) : 0.f;
      float e3 = mv ? __expf(acc[3]) : 0.f;
      eT[quad * 4 + 0][col] = e0;
      eT[quad * 4 + 1][col] = e1;
      eT[quad * 4 + 2][col] = e2;
      eT[quad * 4 + 3][col] = e3;
      s0 += e0; s1 += e1; s2 += e2; s3 += e3;
    }
  }
  s0 += __shfl_xor(s0, 1); s0 += __shfl_xor(s0, 2); s0 += __shfl_xor(s0, 4); s0 += __shfl_xor(s0, 8);
  s1 += __shfl_xor(s1, 1); s1 += __shfl_xor(s1, 2); s1 += __shfl_xor(s1, 4); s1 += __shfl_xor(s1, 8);
  s2 += __shfl_xor(s2, 1); s2 += __shfl_xor(s2, 2); s2 += __shfl_xor(s2, 4); s2 += __shfl_xor(s2, 8);
  s3 += __shfl_xor(s3, 1); s3 += __shfl_xor(s3, 2); s3 += __shfl_xor(s3, 4); s3 += __shfl_xor(s3, 8);
  if (l16 == 0) {
    sSum[wave][quad * 4 + 0] = s0;
    sSum[wave][quad * 4 + 1] = s1;
    sSum[wave][quad * 4 + 2] = s2;
    sSum[wave][quad * 4 + 3] = s3;
  }
  __syncthreads();

  // ---- phase 3 (issued first): stream normalized attn row `wave` from LDS ----
  {
    float t = 0.f;
#pragma unroll
    for (int w2 = 0; w2 < 16; ++w2) t += sSum[w2][wave];
    const float ir = 1.0f / t;
    float* dst = attn + (headoff + qbase + wave) * NS;
    const float* src = &eT[wave][0];
#pragma unroll
    for (int c = 0; c < NS; c += 256) {
      f32x4 v4 = *(const f32x4*)(src + c + lane * 4);
      v4 *= ir;
      *(f32x4*)(dst + c + lane * 4) = v4;
    }
  }

  // ---- phase 2: PV with unnormalized e; wave = (kh, dt) ----
  const int dt = wave & 3, kh = wave >> 2;
  f32x4 acco = {0.f, 0.f, 0.f, 0.f};
  const bf16_t* vrow = vhead + (long)(dt * 16 + l16) * NS;
  const int kb2 = kh * 512;
#pragma unroll 2
  for (int k0 = kb2; k0 < kb2 + 512; k0 += 64) {
    const float* ep = &eT[l16][k0 + quad * 8];
    f32x4 ea = *(const f32x4*)ep;
    f32x4 eb = *(const f32x4*)(ep + 4);
    f32x4 ec = *(const f32x4*)(ep + 32);
    f32x4 ed = *(const f32x4*)(ep + 36);
    bf16x8 af0, af1;
#pragma unroll
    for (int i = 0; i < 4; ++i) {
      af0[i] = (bf16_t)ea[i]; af0[i + 4] = (bf16_t)eb[i];
      af1[i] = (bf16_t)ec[i]; af1[i + 4] = (bf16_t)ed[i];
    }
    acco = MFMA16(af0, load8(vrow + k0 + quad * 8), acco, 0, 0, 0);
    acco = MFMA16(af1, load8(vrow + k0 + 32 + quad * 8), acco, 0, 0, 0);
  }
  if (kh > 0) *(f32x4*)&red[kh - 1][dt][lane][0] = acco;
  __syncthreads();
  if (kh == 0) {
    f32x4 o = acco;
    o += *(const f32x4*)&red[0][dt][lane][0];
    o += *(const f32x4*)&red[1][dt][lane][0];
    o += *(const f32x4*)&red[2][dt][lane][0];
    float invr[4];
#pragma unroll
    for (int r = 0; r < 4; ++r) {
      const int row = quad * 4 + r;
      float t = 0.f;
#pragma unroll
      for (int w2 = 0; w2 < 16; ++w2) t += sSum[w2][row];
      invr[r] = 1.0f / t;
    }
#pragma unroll
    for (int r = 0; r < 4; ++r)
      o_ws[(long)(b * NS + qbase + quad * 4 + r) * NP + h * NDH + dt * 16 + l16] =
          (bf16_t)(o[r] * invr[r]);
  }
}

// ---------------------------------------------------------------------------
// out = O @ Wo  (128x128 LDS-staged GEMM, fp32 store to d_out)
// ---------------------------------------------------------------------------
__global__ __launch_bounds__(256) void k_out(
    const bf16_t* __restrict__ o_ws, const bf16_t* __restrict__ wto,
    float* __restrict__ out)
{
  __shared__ __align__(16) bf16_t As[128][64];
  __shared__ __align__(16) bf16_t Bs[128][64];
  const int tm = blockIdx.x * 128, tn = blockIdx.y * 128;

  f32x4 acc[4][4];
#pragma unroll
  for (int i = 0; i < 4; ++i)
#pragma unroll
    for (int j = 0; j < 4; ++j) acc[i][j] = (f32x4){0.f, 0.f, 0.f, 0.f};

  gemm_128x128<NP>(o_ws, wto, tm, tn, As, Bs, acc);

  const int wave = threadIdx.x >> 6, lane = threadIdx.x & 63;
  const int l16 = lane & 15, quad = lane >> 4;
  const int wr = wave >> 1, wc = wave & 1;
#pragma unroll
  for (int mi = 0; mi < 4; ++mi) {
    const int m0 = tm + wr * 64 + mi * 16 + quad * 4;
#pragma unroll
    for (int ni = 0; ni < 4; ++ni) {
      const int n = tn + wc * 64 + ni * 16 + l16;
#pragma unroll
      for (int r = 0; r < 4; ++r)
        out[(long)(m0 + r) * NP + n] = acc[mi][ni][r];
    }
  }
}

// ---------------------------------------------------------------------------
extern "C" void kernel_launch(void* const* d_in, const int* in_sizes, int n_in,
                              void* d_out, int out_size, void* d_ws, size_t ws_size,
                              hipStream_t stream) {
  const float* x    = (const float*)d_in[0];
  const int*   mask = (const int*)d_in[1];
  const float* Wq   = (const float*)d_in[2];
  const float* Wk   = (const float*)d_in[3];
  const float* Wv   = (const float*)d_in[4];
  const float* Wo   = (const float*)d_in[5];

  float* out  = (float*)d_out;                    // [B,S,P] fp32
  float* attn = out + (long)NM * NP;              // [B,H,S,S] fp32

  char* ws = (char*)d_ws;
  const size_t MB = 1024 * 1024;
  bf16_t* x_bf  = (bf16_t*)(ws);                  // 8 MB (aliased as o_ws later)
  bf16_t* wtq   = (bf16_t*)(ws + 8  * MB);        // 2 MB each
  bf16_t* wtk   = (bf16_t*)(ws + 10 * MB);
  bf16_t* wtv   = (bf16_t*)(ws + 12 * MB);
  bf16_t* wto   = (bf16_t*)(ws + 14 * MB);
  bf16_t* q_ws  = (bf16_t*)(ws + 16 * MB);        // 8 MB [b][h][s][dh], pre-scaled 1/8
  bf16_t* k_ws  = (bf16_t*)(ws + 24 * MB);        // 8 MB [b][h][s][dh]
  bf16_t* v_ws  = (bf16_t*)(ws + 32 * MB);        // 8 MB [b][h][dh][s]
  bf16_t* o_ws  = x_bf;  // safe: x_bf consumed by k_gemm_proj before k_attn_pv writes

  k_cast<<<1024, 256, 0, stream>>>(x, x_bf);
  k_wt<<<dim3(ND / 64, NP / 64, 4), 256, 0, stream>>>(
      Wq, Wk, Wv, Wo, wtq, wtk, wtv, wto);
  k_gemm_proj<<<dim3(NM / 128, NP / 128, 3), 256, 0, stream>>>(
      x_bf, wtq, wtk, wtv, q_ws, k_ws, v_ws);
  k_attn_pv<<<dim3(NS / 16, NH, NB), 1024, 0, stream>>>(
      q_ws, k_ws, v_ws, mask, attn, o_ws);
  k_out<<<dim3(NM / 128, NP / 128), 256, 0, stream>>>(o_ws, wto, out);
}